// Round 11
// baseline (68.099 us; speedup 1.0000x reference)
//
#include <hip/hip_runtime.h>
#include <hip/hip_fp16.h>
#include <math.h>

#define TY 4
#define TX 64
#define AH (TY + 6)   // 10 ang rows
#define AW (TX + 6)   // 70 ang cols
#define PH (TY + 3)   // 7  pooled rows
#define PW (TX + 3)   // 67 pooled cols
#define H 512
#define W 512
#define HW (H * W)

// LDS layout (bytes):
//   [0, 21440)        s_angx  f32 [AH][2][PW][4]    (10*2*67*16)
//   [21440, 32640)    s_ang   f16x8 [AH][AW]        (700*16)   -- dead after stage 2
//   [21440, 28944)    s_pool16 f16x4 [PH][2][PW]    (14*67*8)  -- aliases s_ang
#define ANGX_OFF 0
#define ANG_OFF  21440
#define POOL_OFF 21440
#define SMEM_BYTES 32640

__device__ __forceinline__ unsigned short f2h(float f) {
    return __half_as_ushort(__float2half(f));
}
__device__ __forceinline__ float h2f_lo(unsigned int u) {
    return __half2float(__ushort_as_half((unsigned short)(u & 0xffffu)));
}
__device__ __forceinline__ float h2f_hi(unsigned int u) {
    return __half2float(__ushort_as_half((unsigned short)(u >> 16)));
}

__global__ __launch_bounds__(256, 4) void sift_kernel(const float* __restrict__ x,
                                                      float* __restrict__ out) {
    __shared__ __align__(16) char smem[SMEM_BYTES];
    float4* s_angx  = (float4*)(smem + ANGX_OFF);   // [(ay*2+dh)*PW + pxl]
    uint4*  s_ang   = (uint4*)(smem + ANG_OFF);     // [ay*AW + ax], 8 ch f16
    uint2*  s_pool16= (uint2*)(smem + POOL_OFF);    // [(pyl*2+dh)*PW + pxl], 4 ch f16

    const int tid = threadIdx.x;
    const int x0 = blockIdx.x * TX;
    const int y0 = blockIdx.y * TY;
    const int b  = blockIdx.z;
    const float* __restrict__ xb = x + (size_t)b * HW;

    const float K1[4] = {0.25f, 0.75f, 0.75f, 0.25f};

    // ---- Stage 1: gradient + soft-bin (poly atan), packed f16x8 scatter ----
    for (int i = tid; i < AH * AW; i += 256) {
        int ay = i / AW, ax = i - ay * AW;
        int gy = y0 - 3 + ay, gx = x0 - 3 + ax;
        float w0 = 0.f, w1 = 0.f;
        int bin = 0;
        if (gy >= 0 && gy < H && gx >= 0 && gx < W) {
            int gxm = gx - 1 < 0 ? 0 : gx - 1;
            int gxp_ = gx + 1 > W - 1 ? W - 1 : gx + 1;
            int gym = gy - 1 < 0 ? 0 : gy - 1;
            int gyp_ = gy + 1 > H - 1 ? H - 1 : gy + 1;
            float gxv = 0.5f * (xb[gy * W + gxp_] - xb[gy * W + gxm]);
            float gyv = 0.5f * (xb[gyp_ * W + gx] - xb[gym * W + gx]);
            float mag = __builtin_amdgcn_sqrtf(gxv * gxv + gyv * gyv + 1e-10f);
            float gxe = gxv + 1e-10f;
            float axv = fabsf(gxe), ayv = fabsf(gyv);
            float mn = fminf(axv, ayv), mx = fmaxf(axv, ayv);
            float t = mn * __builtin_amdgcn_rcpf(fmaxf(mx, 1e-30f));
            float t2 = t * t;
            float p = t * fmaf(t2, fmaf(t2, fmaf(t2, fmaf(t2,
                        fmaf(t2, -0.01492385f, 0.06704027f),
                        -0.14824684f), 0.2464268f), -0.4235113f), 1.2732106f);
            float q = (ayv > axv) ? (2.0f - p) : p;
            q = (gxe < 0.0f) ? (4.0f - q) : q;
            float o = (gyv < 0.0f) ? (0.0f - q) : q;
            float of = floorf(o);
            float wo1 = o - of;
            bin = ((int)of) & 7;
            w0 = (1.f - wo1) * mag;
            w1 = wo1 * mag;
        }
        unsigned short h0 = f2h(w0), h1 = f2h(w1);
        unsigned int pack01 = (unsigned int)h0 | ((unsigned int)h1 << 16);
        unsigned int ph0 = (unsigned int)h0 << 16;
        unsigned int pl1 = (unsigned int)h1;
        int j0 = bin >> 1;
        int j1 = ((bin + 1) & 7) >> 1;
        bool ev = (bin & 1) == 0;
        uint4 d;
        d.x = ev ? (j0 == 0 ? pack01 : 0u) : ((j0 == 0 ? ph0 : 0u) | (j1 == 0 ? pl1 : 0u));
        d.y = ev ? (j0 == 1 ? pack01 : 0u) : ((j0 == 1 ? ph0 : 0u) | (j1 == 1 ? pl1 : 0u));
        d.z = ev ? (j0 == 2 ? pack01 : 0u) : ((j0 == 2 ? ph0 : 0u) | (j1 == 2 ? pl1 : 0u));
        d.w = ev ? (j0 == 3 ? pack01 : 0u) : ((j0 == 3 ? ph0 : 0u) | (j1 == 3 ? pl1 : 0u));
        s_ang[i] = d;
    }
    __syncthreads();

    // ---- Stage 2: horizontal 1D conv (f16 in, f32 out) ----
    for (int i = tid; i < AH * PW; i += 256) {
        int ay = i / PW, pxl = i - ay * PW;
        float acc[8] = {0.f, 0.f, 0.f, 0.f, 0.f, 0.f, 0.f, 0.f};
        int base = ay * AW + pxl;
        #pragma unroll
        for (int v = 0; v < 4; ++v) {
            uint4 q = s_ang[base + v];
            float k = K1[v];
            acc[0] = fmaf(k, h2f_lo(q.x), acc[0]);
            acc[1] = fmaf(k, h2f_hi(q.x), acc[1]);
            acc[2] = fmaf(k, h2f_lo(q.y), acc[2]);
            acc[3] = fmaf(k, h2f_hi(q.y), acc[3]);
            acc[4] = fmaf(k, h2f_lo(q.z), acc[4]);
            acc[5] = fmaf(k, h2f_hi(q.z), acc[5]);
            acc[6] = fmaf(k, h2f_lo(q.w), acc[6]);
            acc[7] = fmaf(k, h2f_hi(q.w), acc[7]);
        }
        s_angx[(ay * 2 + 0) * PW + pxl] = make_float4(acc[0], acc[1], acc[2], acc[3]);
        s_angx[(ay * 2 + 1) * PW + pxl] = make_float4(acc[4], acc[5], acc[6], acc[7]);
    }
    __syncthreads();

    // ---- Stage 3: vertical conv (f32) -> pooled, packed f16x4 + boundary zero ----
    for (int i = tid; i < PH * PW * 2; i += 256) {
        int row = i / PW, pxl = i - row * PW;   // row = pyl*2 + dh
        int pyl = row >> 1;
        float4 s = make_float4(0.f, 0.f, 0.f, 0.f);
        #pragma unroll
        for (int u = 0; u < 4; ++u) {
            float4 a = s_angx[((pyl + u) * 2 + (row & 1)) * PW + pxl];
            float k = K1[u];
            s.x = fmaf(k, a.x, s.x);
            s.y = fmaf(k, a.y, s.y);
            s.z = fmaf(k, a.z, s.z);
            s.w = fmaf(k, a.w, s.w);
        }
        bool valid = ((unsigned)(y0 - 1 + pyl) <= 512u) && ((unsigned)(x0 - 1 + pxl) <= 512u);
        if (!valid) s = make_float4(0.f, 0.f, 0.f, 0.f);
        uint2 pk;
        pk.x = (unsigned int)f2h(s.x) | ((unsigned int)f2h(s.y) << 16);
        pk.y = (unsigned int)f2h(s.z) | ((unsigned int)f2h(s.w) << 16);
        s_pool16[row * PW + pxl] = pk;
    }
    __syncthreads();

    // ---- Epilogue: 1 thread = 1 pixel (all 128 ch), no shuffles,
    //      128 single-segment 256B plane-sequential stores per wave ----
    const int wv   = tid >> 6;     // row ty
    const int lane = tid & 63;     // x
    const int yy = y0 + wv;
    const int xx = x0 + lane;

    uint2 r[32];                   // [dh*16 + ky*4 + kx], 4 ch f16 each = 64 VGPR
    float ssq = 0.f;
    #pragma unroll
    for (int dh = 0; dh < 2; ++dh) {
        #pragma unroll
        for (int ky = 0; ky < 4; ++ky) {
            #pragma unroll
            for (int kx = 0; kx < 4; ++kx) {
                uint2 q = s_pool16[((wv + ky) * 2 + dh) * PW + (lane + kx)];
                r[dh * 16 + ky * 4 + kx] = q;
                float a0 = h2f_lo(q.x), a1 = h2f_hi(q.x);
                float a2 = h2f_lo(q.y), a3 = h2f_hi(q.y);
                ssq = fmaf(a0, a0, fmaf(a1, a1, fmaf(a2, a2, fmaf(a3, a3, ssq))));
            }
        }
    }
    float inv = __builtin_amdgcn_rsqf(fmaxf(ssq, 1e-24f));

    float su = 0.f;
    #pragma unroll
    for (int m = 0; m < 32; ++m) {
        uint2 q = r[m];
        su += fminf(h2f_lo(q.x) * inv, 0.2f) + fminf(h2f_hi(q.x) * inv, 0.2f)
            + fminf(h2f_lo(q.y) * inv, 0.2f) + fminf(h2f_hi(q.y) * inv, 0.2f);
    }
    float rs = __builtin_amdgcn_rcpf(fmaxf(su, 1e-12f));

    // c = dh*64 + dd*16 + (ky*4+kx); walk c = 0..127 sequentially
    float* __restrict__ op = out + (size_t)b * 128 * HW + (size_t)yy * W + xx;
    #pragma unroll
    for (int dh = 0; dh < 2; ++dh) {
        #pragma unroll
        for (int dd = 0; dd < 4; ++dd) {
            #pragma unroll
            for (int m = 0; m < 16; ++m) {
                uint2 q = r[dh * 16 + m];
                float comp = (dd == 0) ? h2f_lo(q.x) : (dd == 1) ? h2f_hi(q.x)
                           : (dd == 2) ? h2f_lo(q.y) : h2f_hi(q.y);
                float u = fminf(comp * inv, 0.2f);
                float val = __builtin_amdgcn_sqrtf(fmaf(u, rs, 1e-10f));
                op[(size_t)((dh * 4 + dd) * 16 + m) * HW] = val;
            }
        }
    }
}

extern "C" void kernel_launch(void* const* d_in, const int* in_sizes, int n_in,
                              void* d_out, int out_size, void* d_ws, size_t ws_size,
                              hipStream_t stream) {
    const float* x = (const float*)d_in[0];
    float* out = (float*)d_out;
    const int B = in_sizes[0] / (H * W);   // = 2
    dim3 grid(W / TX, H / TY, B);
    dim3 block(256);
    hipLaunchKernelGGL(sift_kernel, grid, block, 0, stream, x, out);
    (void)n_in; (void)out_size; (void)d_ws; (void)ws_size;
}

// Round 12
// 49.396 us; speedup vs baseline: 1.3786x; 1.3786x over previous
//
#include <hip/hip_runtime.h>
#include <hip/hip_fp16.h>
#include <math.h>

#define TY 4
#define TX 64
#define AH (TY + 6)   // 10 ang rows
#define AW (TX + 6)   // 70 ang cols
#define PH (TY + 3)   // 7  pooled rows
#define PW (TX + 3)   // 67 pooled cols
#define H 512
#define W 512
#define HW (H * W)

// LDS layout (bytes):
//   [0, 21440)        s_angx  f32 [AH][2][PW][4]    (10*2*67*16)
//   [21440, 32640)    s_ang   f16x8 [AH][AW]        (700*16)   -- dead after stage 2
//   [21440, 28944)    s_pool16 f16x4 [PH][2][PW]    (14*67*8)  -- aliases s_ang
#define ANGX_OFF 0
#define ANG_OFF  21440
#define POOL_OFF 21440
#define SMEM_BYTES 32640

__device__ __forceinline__ unsigned short f2h(float f) {
    return __half_as_ushort(__float2half(f));
}
__device__ __forceinline__ float h2f_lo(unsigned int u) {
    return __half2float(__ushort_as_half((unsigned short)(u & 0xffffu)));
}
__device__ __forceinline__ float h2f_hi(unsigned int u) {
    return __half2float(__ushort_as_half((unsigned short)(u >> 16)));
}

__global__ __launch_bounds__(256, 5) void sift_kernel(const float* __restrict__ x,
                                                      float* __restrict__ out) {
    __shared__ __align__(16) char smem[SMEM_BYTES];
    float4* s_angx  = (float4*)(smem + ANGX_OFF);   // [(ay*2+dh)*PW + pxl]
    uint4*  s_ang   = (uint4*)(smem + ANG_OFF);     // [ay*AW + ax], 8 ch f16
    uint2*  s_pool16= (uint2*)(smem + POOL_OFF);    // [(pyl*2+dh)*PW + pxl], 4 ch f16

    const int tid = threadIdx.x;
    const int x0 = blockIdx.x * TX;
    const int y0 = blockIdx.y * TY;
    const int b  = blockIdx.z;
    const float* __restrict__ xb = x + (size_t)b * HW;

    const float K1[4] = {0.25f, 0.75f, 0.75f, 0.25f};

    // ---- Stage 1: gradient + soft-bin (poly atan), packed f16x8 scatter ----
    for (int i = tid; i < AH * AW; i += 256) {
        int ay = i / AW, ax = i - ay * AW;
        int gy = y0 - 3 + ay, gx = x0 - 3 + ax;
        float w0 = 0.f, w1 = 0.f;
        int bin = 0;
        if (gy >= 0 && gy < H && gx >= 0 && gx < W) {
            int gxm = gx - 1 < 0 ? 0 : gx - 1;
            int gxp_ = gx + 1 > W - 1 ? W - 1 : gx + 1;
            int gym = gy - 1 < 0 ? 0 : gy - 1;
            int gyp_ = gy + 1 > H - 1 ? H - 1 : gy + 1;
            float gxv = 0.5f * (xb[gy * W + gxp_] - xb[gy * W + gxm]);
            float gyv = 0.5f * (xb[gyp_ * W + gx] - xb[gym * W + gx]);
            float mag = __builtin_amdgcn_sqrtf(gxv * gxv + gyv * gyv + 1e-10f);
            float gxe = gxv + 1e-10f;
            float axv = fabsf(gxe), ayv = fabsf(gyv);
            float mn = fminf(axv, ayv), mx = fmaxf(axv, ayv);
            float t = mn * __builtin_amdgcn_rcpf(fmaxf(mx, 1e-30f));
            float t2 = t * t;
            float p = t * fmaf(t2, fmaf(t2, fmaf(t2, fmaf(t2,
                        fmaf(t2, -0.01492385f, 0.06704027f),
                        -0.14824684f), 0.2464268f), -0.4235113f), 1.2732106f);
            float q = (ayv > axv) ? (2.0f - p) : p;
            q = (gxe < 0.0f) ? (4.0f - q) : q;
            float o = (gyv < 0.0f) ? (0.0f - q) : q;
            float of = floorf(o);
            float wo1 = o - of;
            bin = ((int)of) & 7;
            w0 = (1.f - wo1) * mag;
            w1 = wo1 * mag;
        }
        unsigned short h0 = f2h(w0), h1 = f2h(w1);
        unsigned int pack01 = (unsigned int)h0 | ((unsigned int)h1 << 16);
        unsigned int ph0 = (unsigned int)h0 << 16;
        unsigned int pl1 = (unsigned int)h1;
        int j0 = bin >> 1;
        int j1 = ((bin + 1) & 7) >> 1;
        bool ev = (bin & 1) == 0;
        uint4 d;
        d.x = ev ? (j0 == 0 ? pack01 : 0u) : ((j0 == 0 ? ph0 : 0u) | (j1 == 0 ? pl1 : 0u));
        d.y = ev ? (j0 == 1 ? pack01 : 0u) : ((j0 == 1 ? ph0 : 0u) | (j1 == 1 ? pl1 : 0u));
        d.z = ev ? (j0 == 2 ? pack01 : 0u) : ((j0 == 2 ? ph0 : 0u) | (j1 == 2 ? pl1 : 0u));
        d.w = ev ? (j0 == 3 ? pack01 : 0u) : ((j0 == 3 ? ph0 : 0u) | (j1 == 3 ? pl1 : 0u));
        s_ang[i] = d;
    }
    __syncthreads();

    // ---- Stage 2: horizontal 1D conv (f16 in, f32 out) ----
    for (int i = tid; i < AH * PW; i += 256) {
        int ay = i / PW, pxl = i - ay * PW;
        float acc[8] = {0.f, 0.f, 0.f, 0.f, 0.f, 0.f, 0.f, 0.f};
        int base = ay * AW + pxl;
        #pragma unroll
        for (int v = 0; v < 4; ++v) {
            uint4 q = s_ang[base + v];
            float k = K1[v];
            acc[0] = fmaf(k, h2f_lo(q.x), acc[0]);
            acc[1] = fmaf(k, h2f_hi(q.x), acc[1]);
            acc[2] = fmaf(k, h2f_lo(q.y), acc[2]);
            acc[3] = fmaf(k, h2f_hi(q.y), acc[3]);
            acc[4] = fmaf(k, h2f_lo(q.z), acc[4]);
            acc[5] = fmaf(k, h2f_hi(q.z), acc[5]);
            acc[6] = fmaf(k, h2f_lo(q.w), acc[6]);
            acc[7] = fmaf(k, h2f_hi(q.w), acc[7]);
        }
        s_angx[(ay * 2 + 0) * PW + pxl] = make_float4(acc[0], acc[1], acc[2], acc[3]);
        s_angx[(ay * 2 + 1) * PW + pxl] = make_float4(acc[4], acc[5], acc[6], acc[7]);
    }
    __syncthreads();

    // ---- Stage 3: vertical conv (f32) -> pooled, packed f16x4 + boundary zero ----
    for (int i = tid; i < PH * PW * 2; i += 256) {
        int row = i / PW, pxl = i - row * PW;   // row = pyl*2 + dh
        int pyl = row >> 1;
        float4 s = make_float4(0.f, 0.f, 0.f, 0.f);
        #pragma unroll
        for (int u = 0; u < 4; ++u) {
            float4 a = s_angx[((pyl + u) * 2 + (row & 1)) * PW + pxl];
            float k = K1[u];
            s.x = fmaf(k, a.x, s.x);
            s.y = fmaf(k, a.y, s.y);
            s.z = fmaf(k, a.z, s.z);
            s.w = fmaf(k, a.w, s.w);
        }
        bool valid = ((unsigned)(y0 - 1 + pyl) <= 512u) && ((unsigned)(x0 - 1 + pxl) <= 512u);
        if (!valid) s = make_float4(0.f, 0.f, 0.f, 0.f);
        uint2 pk;
        pk.x = (unsigned int)f2h(s.x) | ((unsigned int)f2h(s.y) << 16);
        pk.y = (unsigned int)f2h(s.z) | ((unsigned int)f2h(s.w) << 16);
        s_pool16[row * PW + pxl] = pk;
    }
    __syncthreads();

    // ---- Epilogue: 2 threads per pixel (channel halves), packed-f16 r cache ----
    const int w  = tid >> 6;
    const int l  = tid & 63;
    const int dh = l >> 5;
    const int tx = 32 * (w & 1) + (l & 31);
    const int xx = x0 + tx;

    #pragma unroll
    for (int pp = 0; pp < 2; ++pp) {
        const int ty = 2 * pp + (w >> 1);
        const int yy = y0 + ty;
        uint2 r[16];                 // 32 VGPR: 4 ch f16 per (ky,kx)
        float ssq = 0.f;
        #pragma unroll
        for (int ky = 0; ky < 4; ++ky) {
            #pragma unroll
            for (int kx = 0; kx < 4; ++kx) {
                uint2 q = s_pool16[((ty + ky) * 2 + dh) * PW + (tx + kx)];
                r[ky * 4 + kx] = q;
                float a0 = h2f_lo(q.x), a1 = h2f_hi(q.x);
                float a2 = h2f_lo(q.y), a3 = h2f_hi(q.y);
                ssq = fmaf(a0, a0, fmaf(a1, a1, fmaf(a2, a2, fmaf(a3, a3, ssq))));
            }
        }
        ssq += __shfl_xor(ssq, 32, 64);
        float inv = __builtin_amdgcn_rsqf(fmaxf(ssq, 1e-24f));
        float su = 0.f;
        #pragma unroll
        for (int m = 0; m < 16; ++m) {
            uint2 q = r[m];
            su += fminf(h2f_lo(q.x) * inv, 0.2f) + fminf(h2f_hi(q.x) * inv, 0.2f)
                + fminf(h2f_lo(q.y) * inv, 0.2f) + fminf(h2f_hi(q.y) * inv, 0.2f);
        }
        su += __shfl_xor(su, 32, 64);
        float rs = __builtin_amdgcn_rcpf(fmaxf(su, 1e-12f));
        // c = dh*64 + dd*16 + m ; plain stores through L2
        float* __restrict__ op = out + ((size_t)b * 128 + dh * 64) * (size_t)HW
                                     + (size_t)yy * W + xx;
        #pragma unroll
        for (int dd = 0; dd < 4; ++dd) {
            #pragma unroll
            for (int m = 0; m < 16; ++m) {
                uint2 q = r[m];
                float comp = (dd == 0) ? h2f_lo(q.x) : (dd == 1) ? h2f_hi(q.x)
                           : (dd == 2) ? h2f_lo(q.y) : h2f_hi(q.y);
                float u = fminf(comp * inv, 0.2f);
                float val = __builtin_amdgcn_sqrtf(fmaf(u, rs, 1e-10f));
                op[(size_t)(dd * 16 + m) * HW] = val;
            }
        }
    }
}

extern "C" void kernel_launch(void* const* d_in, const int* in_sizes, int n_in,
                              void* d_out, int out_size, void* d_ws, size_t ws_size,
                              hipStream_t stream) {
    const float* x = (const float*)d_in[0];
    float* out = (float*)d_out;
    const int B = in_sizes[0] / (H * W);   // = 2
    dim3 grid(W / TX, H / TY, B);
    dim3 block(256);
    hipLaunchKernelGGL(sift_kernel, grid, block, 0, stream, x, out);
    (void)n_in; (void)out_size; (void)d_ws; (void)ws_size;
}